// Round 2
// baseline (2950.524 us; speedup 1.0000x reference)
//
#include <hip/hip_runtime.h>

typedef unsigned int uint;
typedef _Float16 half_t;
typedef __attribute__((ext_vector_type(8))) _Float16 halfx8;
typedef __attribute__((ext_vector_type(4))) float floatx4;

constexpr int BSHIFT  = 9;         // 512 nodes per bucket
constexpr int BNODES  = 1 << BSHIFT;
constexpr int BCAP    = 9216;      // bucket cap: mean 8192 +11 sigma
constexpr int CSTRIDE = 16;        // one counter per 64B line
constexpr int CHUNK   = 8192;      // edges per sort block

// native LDS float atomic add (fire-and-forget). hipcc's atomicAdd lowers to a
// CAS loop for fp32 LDS (no -munsafe-fp-atomics) -> 120cy serial round-trips.
// Generic->LDS: low 32 bits of a generic pointer to __shared__ are the LDS
// byte offset. No "memory" clobber: allows next iteration's gathers to hoist
// above the adds; a waitcnt+clobber fence precedes the final barrier.
__device__ __forceinline__ void lds_fadd(float* p, float v) {
    asm volatile("ds_add_f32 %0, %1" :: "v"((uint)(size_t)p), "v"(v));
}

// ---------------- mega0: sortA | prepW1 | prepW2 | prepWc --------------------
__global__ __launch_bounds__(256) void k_mega0(
    const int* __restrict__ ei,
    const float* __restrict__ W1, const float* __restrict__ W2,
    const float* __restrict__ W3, const float* __restrict__ Wout,
    const float* __restrict__ b3, const float* __restrict__ bout,
    int* __restrict__ bcnt, uint* __restrict__ tmp,
    half_t* __restrict__ Wh1, half_t* __restrict__ Wh2,
    half_t* __restrict__ Whc, float* __restrict__ bc,
    int E, int nSort) {
    __shared__ __align__(16) char smem[45088];
    const int bx = blockIdx.x, t = threadIdx.x;

    if (bx < nSort) {
        // ---- sortA: per-block LDS counting sort of edges into buckets ----
        uint* ent = (uint*)smem;
        unsigned char* bid = (unsigned char*)(smem + 32768);
        int* hist  = (int*)(smem + 40960);
        int* lbase = hist + 256;
        int* lcur  = hist + 512;
        int* gpos  = hist + 768;
        int* wsum  = hist + 1024;
        const int base = bx * CHUNK;
        const int m = min(CHUNK, E - base);
        hist[t] = 0;
        __syncthreads();
        for (int i = t; i < m; i += 256)
            atomicAdd(&hist[ei[E + base + i] >> BSHIFT], 1);
        __syncthreads();
        {
            int lane = t & 63, w = t >> 6;
            int v = hist[t];
            int incl = v;
            for (int dd = 1; dd < 64; dd <<= 1) { int xsh = __shfl_up(incl, dd); if (lane >= dd) incl += xsh; }
            if (lane == 63) wsum[w] = incl;
            __syncthreads();
            int off = 0;
            for (int i = 0; i < w; i++) off += wsum[i];
            int excl = off + incl - v;
            lbase[t] = excl;
            lcur[t]  = excl;
            gpos[t]  = (v > 0) ? atomicAdd(&bcnt[t * CSTRIDE], v) : 0;
        }
        __syncthreads();
        for (int i = t; i < m; i += 256) {
            int s = ei[base + i];
            int d = ei[E + base + i];
            int b = d >> BSHIFT;
            int pos = atomicAdd(&lcur[b], 1);
            ent[pos] = (uint)s | ((uint)(d & (BNODES - 1)) << 17);   // s < 2^17
            bid[pos] = (unsigned char)b;
        }
        __syncthreads();
        for (int i = t; i < m; i += 256) {
            int b = bid[i];
            int g = gpos[b] + (i - lbase[b]);
            if (g < BCAP) tmp[(size_t)b * BCAP + g] = ent[i];
        }
    } else if (bx < nSort + 64) {
        // ---- prepW1: transpose fp32 W1 -> fp16 Wh1 -----------------------
        int i = (bx - nSort) * 256 + t;
        int k = i >> 7, n = i & 127;
        Wh1[n * 128 + k] = (half_t)W1[k * 128 + n];
    } else if (bx < nSort + 128) {
        // ---- prepW2 ------------------------------------------------------
        int i = (bx - nSort - 64) * 256 + t;
        int k = i >> 7, n = i & 127;
        Wh2[n * 128 + k] = (half_t)W2[k * 128 + n];
    } else {
        // ---- prepWc: Wc = W3@Wout fused transpose; bc = b3@Wout+bout -----
        int i = (bx - nSort - 128) * 256 + t;
        if (i < 128 * 64) {
            int r = i >> 6, j = i & 63;
            float s = 0.0f;
            for (int k = 0; k < 128; k++) s += W3[r * 128 + k] * Wout[k * 64 + j];
            Whc[j * 128 + r] = (half_t)s;
        } else if (i < 128 * 64 + 64) {
            int j = i - 128 * 64;
            float s = bout[j];
            for (int k = 0; k < 128; k++) s += b3[k] * Wout[k * 64 + j];
            bc[j] = s;
        }
    }
}

// ---------------- mid: per-bucket histogram -> inv | bucketScan --------------
__global__ __launch_bounds__(256) void k_mid(
    const uint* __restrict__ tmp, const int* __restrict__ bcnt,
    float* __restrict__ inv, int* __restrict__ bbase,
    int* __restrict__ row_ptr, int N, int B) {
    __shared__ int cnt[BNODES];
    int bx = blockIdx.x, t = threadIdx.x;
    if (bx < B) {
        cnt[t] = 0; cnt[t + 256] = 0;
        __syncthreads();
        int m = min(bcnt[bx * CSTRIDE], BCAP);
        const uint* tp = tmp + (size_t)bx * BCAP;
        for (int i = t; i < m; i += 256) atomicAdd(&cnt[tp[i] >> 17], 1);
        __syncthreads();
        int nbase = bx << BSHIFT;
        int n0 = nbase + t, n1 = nbase + t + 256;
        if (n0 < N) inv[n0] = rsqrtf((float)(cnt[t] + 1));       // +1 self-loop
        if (n1 < N) inv[n1] = rsqrtf((float)(cnt[t + 256] + 1));
    } else {
        int* wsum = cnt;   // reuse
        int lane = t & 63, w = t >> 6;
        int v = (t < B) ? min(bcnt[t * CSTRIDE], BCAP) : 0;
        int incl = v;
        for (int d = 1; d < 64; d <<= 1) { int x = __shfl_up(incl, d); if (lane >= d) incl += x; }
        if (lane == 63) wsum[w] = incl;
        __syncthreads();
        int off = 0;
        for (int i = 0; i < w; i++) off += wsum[i];
        int excl = off + incl - v;
        if (t <= B) bbase[t] = excl;
        if (t == B) row_ptr[N] = excl;
    }
}

// ---------------- mega1: gemm1 (fp32 A, single fp16 W, inv epilogue) | B1 ----
__global__ __launch_bounds__(256) void k_mega1(
    const float* __restrict__ A, const half_t* __restrict__ Wh,
    const float* __restrict__ inv, half_t* __restrict__ Out,
    const uint* __restrict__ tmp, const int* __restrict__ bcnt,
    const int* __restrict__ bbase, int* __restrict__ row_ptr,
    int* __restrict__ colv, int N, int nGemm) {
    __shared__ __align__(16) char smem1[128 * 136 * 2];
    const int bx = blockIdx.x, tid = threadIdx.x;

    if (bx >= nGemm) {
        // ---- B1: per-bucket node histogram -> row_ptr; place src into CSR
        int* cnt = (int*)smem1;             // [512]
        int* cur = cnt + BNODES;            // [512]
        int* wsum2 = cur + BNODES;          // [4]
        int b = bx - nGemm, t = tid;
        int base = bbase[b], nbase = b << BSHIFT;
        cnt[t] = 0; cnt[t + 256] = 0;
        __syncthreads();
        int m = min(bcnt[b * CSTRIDE], BCAP);
        const uint* tp = tmp + (size_t)b * BCAP;
        for (int i = t; i < m; i += 256) atomicAdd(&cnt[tp[i] >> 17], 1);
        __syncthreads();
        int lane = t & 63, w = t >> 6;
        int c0 = cnt[2 * t], c1 = cnt[2 * t + 1];
        int v = c0 + c1;
        int incl = v;
        for (int dd = 1; dd < 64; dd <<= 1) { int x = __shfl_up(incl, dd); if (lane >= dd) incl += x; }
        if (lane == 63) wsum2[w] = incl;
        __syncthreads();
        int off = 0;
        for (int i = 0; i < w; i++) off += wsum2[i];
        int excl = off + incl - v;
        int n0 = nbase + 2 * t, n1 = nbase + 2 * t + 1;
        __syncthreads();
        cur[2 * t] = excl; cur[2 * t + 1] = excl + c0;
        if (n0 < N) row_ptr[n0] = base + excl;
        if (n1 < N) row_ptr[n1] = base + excl + c0;
        __syncthreads();
        for (int i = t; i < m; i += 256) {
            uint wv = tp[i];
            int dlo = wv >> 17, s = (int)(wv & 0x1FFFFu);
            int pos = atomicAdd(&cur[dlo], 1);
            // pack src (17b) + dst row-within-32-block (5b) for LDS-accum agg
            colv[base + pos] = s | ((dlo & 31) << 17);
        }
        return;
    }
    // ---- gemm1: single-pass fp16 W, fp32 A -> fp16, inv-scaled epilogue ---
    half_t* lds = (half_t*)smem1;
    for (int i = tid; i < 128 * 16; i += 256) {
        int r = i >> 4, c = i & 15;
        *(halfx8*)&lds[r * 136 + c * 8] = *(const halfx8*)&Wh[(size_t)r * 128 + c * 8];
    }
    __syncthreads();
    const int w = tid >> 6, lane = tid & 63;
    const int q = lane >> 4, m = lane & 15;
    const int rowBase = bx * 128 + w * 32;
    int arow[2];
#pragma unroll
    for (int rt = 0; rt < 2; ++rt) {
        int r = rowBase + rt * 16 + m;
        arow[rt] = (r < N) ? r : (N - 1);
    }
    floatx4 acc[2][8];
#pragma unroll
    for (int rt = 0; rt < 2; ++rt)
#pragma unroll
        for (int ct = 0; ct < 8; ++ct) acc[rt][ct] = (floatx4)0.0f;
#pragma unroll
    for (int kk = 0; kk < 4; ++kk) {
        halfx8 a[2];
#pragma unroll
        for (int rt = 0; rt < 2; ++rt) {
            const float* ap = A + (size_t)arow[rt] * 128 + kk * 32 + q * 8;
            floatx4 f0 = *(const floatx4*)ap;
            floatx4 f1 = *(const floatx4*)(ap + 4);
#pragma unroll
            for (int i = 0; i < 4; i++) { a[rt][i] = (half_t)f0[i]; a[rt][4 + i] = (half_t)f1[i]; }
        }
#pragma unroll
        for (int ct = 0; ct < 8; ++ct) {
            halfx8 bh = *(const halfx8*)&lds[(ct * 16 + m) * 136 + kk * 32 + q * 8];
#pragma unroll
            for (int rt = 0; rt < 2; ++rt)
                acc[rt][ct] = __builtin_amdgcn_mfma_f32_16x16x32_f16(a[rt], bh, acc[rt][ct], 0, 0, 0);
        }
    }
#pragma unroll
    for (int rt = 0; rt < 2; ++rt)
#pragma unroll
        for (int r = 0; r < 4; ++r) {
            int orow = rowBase + rt * 16 + q * 4 + r;
            if (orow < N) {
                float sc = inv[orow];       // fold inv[row] into stored value
#pragma unroll
                for (int ct = 0; ct < 8; ++ct)
                    Out[(size_t)orow * 128 + ct * 16 + m] = (half_t)(sc * acc[rt][ct][r]);
            }
        }
}

// ---- GEMM (fp16 A, single fp16 W): Out = inv[row] * (A @ Wh) ----------------
template <int NOUT>
__global__ __launch_bounds__(256) void k_gemm(const half_t* __restrict__ A,
                                              const half_t* __restrict__ Wh,
                                              const float* __restrict__ inv,
                                              half_t* __restrict__ Out, int nRows) {
    constexpr int CT = NOUT / 16;
    __shared__ __align__(16) half_t lds[NOUT * 136];
    const int tid = threadIdx.x;
    for (int i = tid; i < NOUT * 16; i += 256) {
        int r = i >> 4, c = i & 15;
        *(halfx8*)&lds[r * 136 + c * 8] = *(const halfx8*)&Wh[(size_t)r * 128 + c * 8];
    }
    __syncthreads();
    const int w = tid >> 6, lane = tid & 63;
    const int q = lane >> 4, m = lane & 15;
    const int rowBase = blockIdx.x * 128 + w * 32;
    int arow[2];
#pragma unroll
    for (int rt = 0; rt < 2; ++rt) {
        int r = rowBase + rt * 16 + m;
        arow[rt] = (r < nRows) ? r : (nRows - 1);
    }
    floatx4 acc[2][CT];
#pragma unroll
    for (int rt = 0; rt < 2; ++rt)
#pragma unroll
        for (int ct = 0; ct < CT; ++ct) acc[rt][ct] = (floatx4)0.0f;
#pragma unroll
    for (int kk = 0; kk < 4; ++kk) {
        halfx8 a[2];
#pragma unroll
        for (int rt = 0; rt < 2; ++rt)
            a[rt] = *(const halfx8*)(A + (size_t)arow[rt] * 128 + kk * 32 + q * 8);
#pragma unroll
        for (int ct = 0; ct < CT; ++ct) {
            halfx8 bh = *(const halfx8*)&lds[(ct * 16 + m) * 136 + kk * 32 + q * 8];
#pragma unroll
            for (int rt = 0; rt < 2; ++rt)
                acc[rt][ct] = __builtin_amdgcn_mfma_f32_16x16x32_f16(a[rt], bh, acc[rt][ct], 0, 0, 0);
        }
    }
#pragma unroll
    for (int rt = 0; rt < 2; ++rt)
#pragma unroll
        for (int r = 0; r < 4; ++r) {
            int orow = rowBase + rt * 16 + q * 4 + r;
            if (orow < nRows) {
                float sc = inv[orow];
#pragma unroll
                for (int ct = 0; ct < CT; ++ct)
                    Out[(size_t)orow * NOUT + ct * 16 + m] = (half_t)(sc * acc[rt][ct][r]);
            }
        }
}

// ---- aggregation v3: 32 rows/block, edge-parallel gather, native ds_add_f32 -
// colv entry: src (bits 0..16) | dst-row-within-32 (bits 17..21)
// LDS slot swizzle: p(lrow,ch) = (l2*8 ^ ((lrow&3)<<3)) | ((c + l2)&7)
//   - low-3 rotation by l2 breaks the within-group 4-lanes-per-bank aliasing
//   - XOR by lrow&3 de-overlays the edge groups (random rows)
template <int CH, typename OT, bool RELU>
__global__ __launch_bounds__(256, 8) void k_agg(const half_t* __restrict__ tb,
                                                const int* __restrict__ colv,
                                                const int* __restrict__ row_ptr,
                                                const float* __restrict__ inv,
                                                const float* __restrict__ bias,
                                                OT* __restrict__ out, int N) {
    constexpr int R = 32;          // dst rows per block
    constexpr int L = CH / 8;      // lanes per edge (8 ch each): 16 or 8
    constexpr int G = 64 / L;      // edges per wave-step: 4 or 8
    __shared__ float sacc[R * CH];
    const int tid = threadIdx.x;
    const int d0 = blockIdx.x * R;
    if (d0 >= N) return;

    // zero accumulators
    for (int i = tid; i < R * CH / 4; i += 256)
        *(floatx4*)&sacc[i * 4] = (floatx4)0.0f;
    __syncthreads();

    const int wid = tid >> 6, lane = tid & 63;
    const int grp = lane / L, l2 = lane % L;
    const int dend = (d0 + R < N) ? (d0 + R) : N;
    const int beg = row_ptr[d0], end = row_ptr[dend];

    for (int e0 = beg + wid * 64; e0 < end; e0 += 256) {
        int ce = (e0 + lane < end) ? colv[e0 + lane] : -1;
        int cnt = min(end - e0, 64);
        for (int j = 0; j < cnt; j += 4 * G) {
            int en[4];
            halfx8 pv[4];
#pragma unroll
            for (int u = 0; u < 4; u++) {           // issue all gathers first
                en[u] = __shfl(ce, j + u * G + grp);
                int s = (en[u] >= 0) ? (en[u] & 0x1FFFF) : 0;
                pv[u] = *(const halfx8*)(tb + (size_t)s * CH + l2 * 8);
            }
#pragma unroll
            for (int u = 0; u < 4; u++) {
                if (en[u] >= 0) {                   // group-uniform predicate
                    int lr = (en[u] >> 17) & 31;
                    float* ap = &sacc[lr * CH];
                    int hi = (l2 * 8) ^ ((lr & 3) << 3);
#pragma unroll
                    for (int cc = 0; cc < 8; cc++) {
                        int p = hi | ((cc + l2) & 7);
                        lds_fadd(&ap[p], (float)pv[u][cc]);
                    }
                }
            }
        }
    }
    // drain all outstanding ds_add before any wave crosses the barrier
    asm volatile("s_waitcnt lgkmcnt(0)" ::: "memory");
    __syncthreads();

    // epilogue: + self term, * inv, + bias, relu, store (8 threads per row)
    constexpr int TPR = 256 / R;       // 8
    constexpr int CPT = CH / TPR;      // 16 (CH=128) or 8 (CH=64)
    const int lr = tid / TPR;
    const int ch0 = (tid % TPR) * CPT;
    const int d = d0 + lr;
    if (d < N) {
        float sc = inv[d];
#pragma unroll
        for (int s = 0; s < CPT / 8; s++) {
            int chb = ch0 + s * 8;
            int l2e = chb >> 3;
            int hi = chb ^ ((lr & 3) << 3);   // chb == l2e*8
            halfx8 ps = *(const halfx8*)(tb + (size_t)d * CH + chb);
            floatx4 b0 = *(const floatx4*)(bias + chb);
            floatx4 b1 = *(const floatx4*)(bias + chb + 4);
            float v[8];
#pragma unroll
            for (int c = 0; c < 8; c++) {
                int p = hi | ((c + l2e) & 7);
                float a = sacc[lr * CH + p] + (float)ps[c];
                a = sc * a + ((c < 4) ? b0[c] : b1[c - 4]);
                if (RELU) a = fmaxf(a, 0.0f);
                v[c] = a;
            }
            if constexpr (sizeof(OT) == 2) {
                halfx8 o;
#pragma unroll
                for (int c = 0; c < 8; c++) o[c] = (half_t)v[c];
                *(halfx8*)((half_t*)out + (size_t)d * CH + chb) = o;
            } else {
                floatx4 o0, o1;
#pragma unroll
                for (int c = 0; c < 4; c++) { o0[c] = v[c]; o1[c] = v[c + 4]; }
                *(floatx4*)((float*)out + (size_t)d * CH + chb) = o0;
                *(floatx4*)((float*)out + (size_t)d * CH + chb + 4) = o1;
            }
        }
    }
}

// ---- host -------------------------------------------------------------------
extern "C" void kernel_launch(void* const* d_in, const int* in_sizes, int n_in,
                              void* d_out, int out_size, void* d_ws, size_t ws_size,
                              hipStream_t stream) {
    const int N = in_sizes[0] / 128;   // 100000
    const int E = in_sizes[1] / 2;     // 1600000
    const int B = (N + BNODES - 1) >> BSHIFT;   // 196

    const float* x    = (const float*)d_in[0];
    const int*   ei   = (const int*)d_in[1];
    const float* W1   = (const float*)d_in[2];
    const float* b1   = (const float*)d_in[3];
    const float* W2   = (const float*)d_in[4];
    const float* b2   = (const float*)d_in[5];
    const float* W3   = (const float*)d_in[6];
    const float* b3   = (const float*)d_in[7];
    const float* Wout = (const float*)d_in[8];
    const float* bout = (const float*)d_in[9];
    float* out = (float*)d_out;

    char* p = (char*)d_ws;
    auto alloc = [&](size_t bytes) -> void* {
        void* r = (void*)p;
        p += (bytes + 255) & ~(size_t)255;
        return r;
    };
    int*    bcnt    = (int*)alloc((size_t)B * CSTRIDE * 4);
    int*    bbase   = (int*)alloc(((size_t)B + 1) * 4);
    uint*   tmp     = (uint*)alloc((size_t)B * BCAP * 4);
    int*    colv    = (int*)alloc((size_t)E * 4);
    int*    row_ptr = (int*)alloc(((size_t)N + 1) * 4);
    float*  inv     = (float*)alloc((size_t)N * 4);
    float*  bc      = (float*)alloc(64 * 4);
    half_t* Wh1     = (half_t*)alloc(128 * 128 * 2);
    half_t* Wh2     = (half_t*)alloc(128 * 128 * 2);
    half_t* Whc     = (half_t*)alloc(64 * 128 * 2);
    half_t* hb      = (half_t*)alloc((size_t)N * 128 * 2);
    half_t* tb      = (half_t*)alloc((size_t)N * 128 * 2);

    const int nSort = (E + CHUNK - 1) / CHUNK;   // 196
    const int nGemm = (N + 127) / 128;           // 782
    const int gAgg  = (N + 31) / 32;             // 3125 (32 rows per block)

    hipMemsetAsync(bcnt, 0, (size_t)B * CSTRIDE * 4, stream);
    // mega0: edge sort || weight preps (single fp16 weights)
    k_mega0<<<nSort + 128 + 33, 256, 0, stream>>>(ei, W1, W2, W3, Wout, b3, bout,
                                                  bcnt, tmp, Wh1, Wh2, Whc, bc,
                                                  E, nSort);
    // mid: per-bucket histogram -> inv || bucket scan
    k_mid<<<B + 1, 256, 0, stream>>>(tmp, bcnt, inv, bbase, row_ptr, N, B);
    // mega1: gemm1 (inv-scaled) || B1 (CSR placement, row-packed colv)
    k_mega1<<<nGemm + B, 256, 0, stream>>>(x, Wh1, inv, tb, tmp, bcnt, bbase,
                                           row_ptr, colv, N, nGemm);
    // layer 1 agg
    k_agg<128, half_t, true><<<gAgg, 256, 0, stream>>>(tb, colv, row_ptr, inv, b1, hb, N);
    // layer 2
    k_gemm<128><<<nGemm, 256, 0, stream>>>(hb, Wh2, inv, tb, N);
    k_agg<128, half_t, true><<<gAgg, 256, 0, stream>>>(tb, colv, row_ptr, inv, b2, hb, N);
    // layer 3 fused with output projection
    k_gemm<64><<<nGemm, 256, 0, stream>>>(hb, Whc, inv, tb, N);
    k_agg<64, float, false><<<gAgg, 256, 0, stream>>>(tb, colv, row_ptr, inv, bc, out, N);
}

// Round 3
// 362.017 us; speedup vs baseline: 8.1502x; 8.1502x over previous
//
#include <hip/hip_runtime.h>

typedef unsigned int uint;
typedef _Float16 half_t;
typedef __attribute__((ext_vector_type(8))) _Float16 halfx8;
typedef __attribute__((ext_vector_type(4))) float floatx4;
typedef __attribute__((ext_vector_type(4))) uint uintx4;

constexpr int BSHIFT  = 9;         // 512 nodes per bucket
constexpr int BNODES  = 1 << BSHIFT;
constexpr int BCAP    = 9216;      // bucket cap: mean 8192 +11 sigma
constexpr int CSTRIDE = 16;        // one counter per 64B line
constexpr int CHUNK   = 8192;      // edges per sort block

// f32 += f16(lo/hi of packed word) * f32 in ONE VOP3P op (v_fma_mix_f32).
// op_sel_hi[0]=1 -> src0 is f16; op_sel[0] picks the half.
__device__ __forceinline__ void fmix_lo(float& a, uint h2, float w) {
    asm("v_fma_mix_f32 %0, %1, %2, %0 op_sel:[0,0,0] op_sel_hi:[1,0,0]"
        : "+v"(a) : "v"(h2), "v"(w));
}
__device__ __forceinline__ void fmix_hi(float& a, uint h2, float w) {
    asm("v_fma_mix_f32 %0, %1, %2, %0 op_sel:[1,0,0] op_sel_hi:[1,0,0]"
        : "+v"(a) : "v"(h2), "v"(w));
}

// ---------------- mega0: sortA | prepW1 | prepW2 | prepWc --------------------
__global__ __launch_bounds__(256) void k_mega0(
    const int* __restrict__ ei,
    const float* __restrict__ W1, const float* __restrict__ W2,
    const float* __restrict__ W3, const float* __restrict__ Wout,
    const float* __restrict__ b3, const float* __restrict__ bout,
    int* __restrict__ bcnt, uint* __restrict__ tmp,
    half_t* __restrict__ Wh1, half_t* __restrict__ Wh2,
    half_t* __restrict__ Whc, float* __restrict__ bc,
    int E, int nSort) {
    __shared__ __align__(16) char smem[45088];
    const int bx = blockIdx.x, t = threadIdx.x;

    if (bx < nSort) {
        // ---- sortA: per-block LDS counting sort of edges into buckets ----
        uint* ent = (uint*)smem;
        unsigned char* bid = (unsigned char*)(smem + 32768);
        int* hist  = (int*)(smem + 40960);
        int* lbase = hist + 256;
        int* lcur  = hist + 512;
        int* gpos  = hist + 768;
        int* wsum  = hist + 1024;
        const int base = bx * CHUNK;
        const int m = min(CHUNK, E - base);
        hist[t] = 0;
        __syncthreads();
        for (int i = t; i < m; i += 256)
            atomicAdd(&hist[ei[E + base + i] >> BSHIFT], 1);
        __syncthreads();
        {
            int lane = t & 63, w = t >> 6;
            int v = hist[t];
            int incl = v;
            for (int dd = 1; dd < 64; dd <<= 1) { int xsh = __shfl_up(incl, dd); if (lane >= dd) incl += xsh; }
            if (lane == 63) wsum[w] = incl;
            __syncthreads();
            int off = 0;
            for (int i = 0; i < w; i++) off += wsum[i];
            int excl = off + incl - v;
            lbase[t] = excl;
            lcur[t]  = excl;
            gpos[t]  = (v > 0) ? atomicAdd(&bcnt[t * CSTRIDE], v) : 0;
        }
        __syncthreads();
        for (int i = t; i < m; i += 256) {
            int s = ei[base + i];
            int d = ei[E + base + i];
            int b = d >> BSHIFT;
            int pos = atomicAdd(&lcur[b], 1);
            ent[pos] = (uint)s | ((uint)(d & (BNODES - 1)) << 17);   // s < 2^17
            bid[pos] = (unsigned char)b;
        }
        __syncthreads();
        for (int i = t; i < m; i += 256) {
            int b = bid[i];
            int g = gpos[b] + (i - lbase[b]);
            if (g < BCAP) tmp[(size_t)b * BCAP + g] = ent[i];
        }
    } else if (bx < nSort + 64) {
        // ---- prepW1: transpose fp32 W1 -> fp16 Wh1 -----------------------
        int i = (bx - nSort) * 256 + t;
        int k = i >> 7, n = i & 127;
        Wh1[n * 128 + k] = (half_t)W1[k * 128 + n];
    } else if (bx < nSort + 128) {
        // ---- prepW2 ------------------------------------------------------
        int i = (bx - nSort - 64) * 256 + t;
        int k = i >> 7, n = i & 127;
        Wh2[n * 128 + k] = (half_t)W2[k * 128 + n];
    } else {
        // ---- prepWc: Wc = W3@Wout fused transpose; bc = b3@Wout+bout -----
        int i = (bx - nSort - 128) * 256 + t;
        if (i < 128 * 64) {
            int r = i >> 6, j = i & 63;
            float s = 0.0f;
            for (int k = 0; k < 128; k++) s += W3[r * 128 + k] * Wout[k * 64 + j];
            Whc[j * 128 + r] = (half_t)s;
        } else if (i < 128 * 64 + 64) {
            int j = i - 128 * 64;
            float s = bout[j];
            for (int k = 0; k < 128; k++) s += b3[k] * Wout[k * 64 + j];
            bc[j] = s;
        }
    }
}

// ---------------- mid: per-bucket histogram -> inv | bucketScan --------------
__global__ __launch_bounds__(256) void k_mid(
    const uint* __restrict__ tmp, const int* __restrict__ bcnt,
    float* __restrict__ inv, int* __restrict__ bbase,
    int* __restrict__ row_ptr, int N, int B) {
    __shared__ int cnt[BNODES];
    int bx = blockIdx.x, t = threadIdx.x;
    if (bx < B) {
        cnt[t] = 0; cnt[t + 256] = 0;
        __syncthreads();
        int m = min(bcnt[bx * CSTRIDE], BCAP);
        const uint* tp = tmp + (size_t)bx * BCAP;
        for (int i = t; i < m; i += 256) atomicAdd(&cnt[tp[i] >> 17], 1);
        __syncthreads();
        int nbase = bx << BSHIFT;
        int n0 = nbase + t, n1 = nbase + t + 256;
        if (n0 < N) inv[n0] = rsqrtf((float)(cnt[t] + 1));       // +1 self-loop
        if (n1 < N) inv[n1] = rsqrtf((float)(cnt[t + 256] + 1));
    } else {
        int* wsum = cnt;   // reuse
        int lane = t & 63, w = t >> 6;
        int v = (t < B) ? min(bcnt[t * CSTRIDE], BCAP) : 0;
        int incl = v;
        for (int d = 1; d < 64; d <<= 1) { int x = __shfl_up(incl, d); if (lane >= d) incl += x; }
        if (lane == 63) wsum[w] = incl;
        __syncthreads();
        int off = 0;
        for (int i = 0; i < w; i++) off += wsum[i];
        int excl = off + incl - v;
        if (t <= B) bbase[t] = excl;
        if (t == B) row_ptr[N] = excl;
    }
}

// ---------------- mega1: gemm1 (fp32 A, single fp16 W, inv epilogue) | B1 ----
__global__ __launch_bounds__(256) void k_mega1(
    const float* __restrict__ A, const half_t* __restrict__ Wh,
    const float* __restrict__ inv, half_t* __restrict__ Out,
    const uint* __restrict__ tmp, const int* __restrict__ bcnt,
    const int* __restrict__ bbase, int* __restrict__ row_ptr,
    int* __restrict__ colv, int N, int nGemm) {
    __shared__ __align__(16) char smem1[128 * 136 * 2];
    const int bx = blockIdx.x, tid = threadIdx.x;

    if (bx >= nGemm) {
        // ---- B1: per-bucket node histogram -> row_ptr; place src into CSR
        int* cnt = (int*)smem1;             // [512]
        int* cur = cnt + BNODES;            // [512]
        int* wsum2 = cur + BNODES;          // [4]
        int b = bx - nGemm, t = tid;
        int base = bbase[b], nbase = b << BSHIFT;
        cnt[t] = 0; cnt[t + 256] = 0;
        __syncthreads();
        int m = min(bcnt[b * CSTRIDE], BCAP);
        const uint* tp = tmp + (size_t)b * BCAP;
        for (int i = t; i < m; i += 256) atomicAdd(&cnt[tp[i] >> 17], 1);
        __syncthreads();
        int lane = t & 63, w = t >> 6;
        int c0 = cnt[2 * t], c1 = cnt[2 * t + 1];
        int v = c0 + c1;
        int incl = v;
        for (int dd = 1; dd < 64; dd <<= 1) { int x = __shfl_up(incl, dd); if (lane >= dd) incl += x; }
        if (lane == 63) wsum2[w] = incl;
        __syncthreads();
        int off = 0;
        for (int i = 0; i < w; i++) off += wsum2[i];
        int excl = off + incl - v;
        int n0 = nbase + 2 * t, n1 = nbase + 2 * t + 1;
        __syncthreads();
        cur[2 * t] = excl; cur[2 * t + 1] = excl + c0;
        if (n0 < N) row_ptr[n0] = base + excl;
        if (n1 < N) row_ptr[n1] = base + excl + c0;
        __syncthreads();
        for (int i = t; i < m; i += 256) {
            uint wv = tp[i];
            int dlo = wv >> 17, s = (int)(wv & 0x1FFFFu);
            int pos = atomicAdd(&cur[dlo], 1);
            colv[base + pos] = s;           // bucket-local, L2-coalesced
        }
        return;
    }
    // ---- gemm1: single-pass fp16 W, fp32 A -> fp16, inv-scaled epilogue ---
    half_t* lds = (half_t*)smem1;
    for (int i = tid; i < 128 * 16; i += 256) {
        int r = i >> 4, c = i & 15;
        *(halfx8*)&lds[r * 136 + c * 8] = *(const halfx8*)&Wh[(size_t)r * 128 + c * 8];
    }
    __syncthreads();
    const int w = tid >> 6, lane = tid & 63;
    const int q = lane >> 4, m = lane & 15;
    const int rowBase = bx * 128 + w * 32;
    int arow[2];
#pragma unroll
    for (int rt = 0; rt < 2; ++rt) {
        int r = rowBase + rt * 16 + m;
        arow[rt] = (r < N) ? r : (N - 1);
    }
    floatx4 acc[2][8];
#pragma unroll
    for (int rt = 0; rt < 2; ++rt)
#pragma unroll
        for (int ct = 0; ct < 8; ++ct) acc[rt][ct] = (floatx4)0.0f;
#pragma unroll
    for (int kk = 0; kk < 4; ++kk) {
        halfx8 a[2];
#pragma unroll
        for (int rt = 0; rt < 2; ++rt) {
            const float* ap = A + (size_t)arow[rt] * 128 + kk * 32 + q * 8;
            floatx4 f0 = *(const floatx4*)ap;
            floatx4 f1 = *(const floatx4*)(ap + 4);
#pragma unroll
            for (int i = 0; i < 4; i++) { a[rt][i] = (half_t)f0[i]; a[rt][4 + i] = (half_t)f1[i]; }
        }
#pragma unroll
        for (int ct = 0; ct < 8; ++ct) {
            halfx8 bh = *(const halfx8*)&lds[(ct * 16 + m) * 136 + kk * 32 + q * 8];
#pragma unroll
            for (int rt = 0; rt < 2; ++rt)
                acc[rt][ct] = __builtin_amdgcn_mfma_f32_16x16x32_f16(a[rt], bh, acc[rt][ct], 0, 0, 0);
        }
    }
#pragma unroll
    for (int rt = 0; rt < 2; ++rt)
#pragma unroll
        for (int r = 0; r < 4; ++r) {
            int orow = rowBase + rt * 16 + q * 4 + r;
            if (orow < N) {
                float sc = inv[orow];       // fold inv[row] into stored value
#pragma unroll
                for (int ct = 0; ct < 8; ++ct)
                    Out[(size_t)orow * 128 + ct * 16 + m] = (half_t)(sc * acc[rt][ct][r]);
            }
        }
}

// ---- GEMM (fp16 A, single fp16 W): Out = inv[row] * (A @ Wh) ----------------
template <int NOUT>
__global__ __launch_bounds__(256) void k_gemm(const half_t* __restrict__ A,
                                              const half_t* __restrict__ Wh,
                                              const float* __restrict__ inv,
                                              half_t* __restrict__ Out, int nRows) {
    constexpr int CT = NOUT / 16;
    __shared__ __align__(16) half_t lds[NOUT * 136];
    const int tid = threadIdx.x;
    for (int i = tid; i < NOUT * 16; i += 256) {
        int r = i >> 4, c = i & 15;
        *(halfx8*)&lds[r * 136 + c * 8] = *(const halfx8*)&Wh[(size_t)r * 128 + c * 8];
    }
    __syncthreads();
    const int w = tid >> 6, lane = tid & 63;
    const int q = lane >> 4, m = lane & 15;
    const int rowBase = blockIdx.x * 128 + w * 32;
    int arow[2];
#pragma unroll
    for (int rt = 0; rt < 2; ++rt) {
        int r = rowBase + rt * 16 + m;
        arow[rt] = (r < nRows) ? r : (nRows - 1);
    }
    floatx4 acc[2][CT];
#pragma unroll
    for (int rt = 0; rt < 2; ++rt)
#pragma unroll
        for (int ct = 0; ct < CT; ++ct) acc[rt][ct] = (floatx4)0.0f;
#pragma unroll
    for (int kk = 0; kk < 4; ++kk) {
        halfx8 a[2];
#pragma unroll
        for (int rt = 0; rt < 2; ++rt)
            a[rt] = *(const halfx8*)(A + (size_t)arow[rt] * 128 + kk * 32 + q * 8);
#pragma unroll
        for (int ct = 0; ct < CT; ++ct) {
            halfx8 bh = *(const halfx8*)&lds[(ct * 16 + m) * 136 + kk * 32 + q * 8];
#pragma unroll
            for (int rt = 0; rt < 2; ++rt)
                acc[rt][ct] = __builtin_amdgcn_mfma_f32_16x16x32_f16(a[rt], bh, acc[rt][ct], 0, 0, 0);
        }
    }
#pragma unroll
    for (int rt = 0; rt < 2; ++rt)
#pragma unroll
        for (int r = 0; r < 4; ++r) {
            int orow = rowBase + rt * 16 + q * 4 + r;
            if (orow < nRows) {
                float sc = inv[orow];
#pragma unroll
                for (int ct = 0; ct < CT; ++ct)
                    Out[(size_t)orow * NOUT + ct * 16 + m] = (half_t)(sc * acc[rt][ct][r]);
            }
        }
}

// ---- aggregation: per-row wave (round-0 structure) + main/tail split --------
// main loop: all 16 edges valid -> no weight shuffles, weight==1
// tail: one predicated 4-deep step (identical to round-0 body)
// accumulate via v_fma_mix_f32 (1 VALU per channel, no separate cvt)
template <int CH, typename OT, bool RELU>
__global__ __launch_bounds__(256) void k_agg(const half_t* __restrict__ tb,
                                             const int* __restrict__ colv,
                                             const int* __restrict__ row_ptr,
                                             const float* __restrict__ inv,
                                             const float* __restrict__ bias,
                                             OT* __restrict__ out, int N) {
    constexpr int L = CH / 8;     // lanes per row (16 or 8)
    constexpr int G = 64 / L;     // edge groups (4 or 8)
    int wid = threadIdx.x >> 6, lane = threadIdx.x & 63;
    int d = blockIdx.x * 4 + wid;
    if (d >= N) return;
    int beg = row_ptr[d], end = row_ptr[d + 1];
    int grp = lane / L;
    int choff = (lane % L) * 8;
    float isd = inv[d];
    float ws0 = (grp == 0) ? 1.0f : 0.0f;   // self term once
    const float one = 1.0f;
    const half_t* tbc = tb + choff;

    float af[8];
    {
        halfx8 ps = *(const halfx8*)(tbc + (size_t)d * CH);
        uintx4 pw = __builtin_bit_cast(uintx4, ps);
#pragma unroll
        for (int c = 0; c < 8; c++) {
            af[c] = 0.0f;
            if (c & 1) fmix_hi(af[c], pw[c >> 1], ws0);
            else       fmix_lo(af[c], pw[c >> 1], ws0);
        }
    }

    for (int e0 = beg; e0 < end; e0 += 64) {
        int me = e0 + lane;
        int sl = 0; float wl = 0.0f;
        if (me < end) { sl = colv[me]; wl = 1.0f; }
        int cnt = end - e0; if (cnt > 64) cnt = 64;
        int j = 0;
        // ---- main: full 4*G-edge steps, all valid, weight == 1 ----------
        for (; j + 4 * G <= cnt; j += 4 * G) {
            int s4[4];
#pragma unroll
            for (int u = 0; u < 4; u++) s4[u] = __shfl(sl, j + u * G + grp);
            halfx8 pv[4];
#pragma unroll
            for (int u = 0; u < 4; u++)
                pv[u] = *(const halfx8*)(tbc + (size_t)s4[u] * CH);
#pragma unroll
            for (int u = 0; u < 4; u++) {
                uintx4 pw = __builtin_bit_cast(uintx4, pv[u]);
#pragma unroll
                for (int c = 0; c < 8; c++) {
                    if (c & 1) fmix_hi(af[c], pw[c >> 1], one);
                    else       fmix_lo(af[c], pw[c >> 1], one);
                }
            }
        }
        // ---- tail: one predicated 4-deep step (<4*G edges remain) -------
        if (j < cnt) {
            int s4[4]; float w4[4];
#pragma unroll
            for (int u = 0; u < 4; u++) {
                int idx = j + u * G + grp;
                s4[u] = __shfl(sl, idx);
                w4[u] = __shfl(wl, idx);
            }
            halfx8 pv[4];
#pragma unroll
            for (int u = 0; u < 4; u++)
                pv[u] = *(const halfx8*)(tbc + (size_t)s4[u] * CH);
#pragma unroll
            for (int u = 0; u < 4; u++) {
                uintx4 pw = __builtin_bit_cast(uintx4, pv[u]);
#pragma unroll
                for (int c = 0; c < 8; c++) {
                    if (c & 1) fmix_hi(af[c], pw[c >> 1], w4[u]);
                    else       fmix_lo(af[c], pw[c >> 1], w4[u]);
                }
            }
        }
    }
#pragma unroll
    for (int msk = L; msk < 64; msk <<= 1)
#pragma unroll
        for (int c = 0; c < 8; c++)
            af[c] += __shfl_xor(af[c], msk);

    if (lane < L) {
        int ch = lane * 8;
        floatx4 b0 = *(const floatx4*)(bias + ch);
        floatx4 b1 = *(const floatx4*)(bias + ch + 4);
#pragma unroll
        for (int c = 0; c < 8; c++) {
            af[c] = isd * af[c] + ((c < 4) ? b0[c] : b1[c - 4]);
            if (RELU) af[c] = fmaxf(af[c], 0.0f);
        }
        if constexpr (sizeof(OT) == 2) {
            halfx8 o;
#pragma unroll
            for (int c = 0; c < 8; c++) o[c] = (half_t)af[c];
            *(halfx8*)((half_t*)out + (size_t)d * CH + ch) = o;
        } else {
            floatx4 o0, o1;
#pragma unroll
            for (int c = 0; c < 4; c++) { o0[c] = af[c]; o1[c] = af[c + 4]; }
            *(floatx4*)((float*)out + (size_t)d * CH + ch) = o0;
            *(floatx4*)((float*)out + (size_t)d * CH + ch + 4) = o1;
        }
    }
}

// ---- host -------------------------------------------------------------------
extern "C" void kernel_launch(void* const* d_in, const int* in_sizes, int n_in,
                              void* d_out, int out_size, void* d_ws, size_t ws_size,
                              hipStream_t stream) {
    const int N = in_sizes[0] / 128;   // 100000
    const int E = in_sizes[1] / 2;     // 1600000
    const int B = (N + BNODES - 1) >> BSHIFT;   // 196

    const float* x    = (const float*)d_in[0];
    const int*   ei   = (const int*)d_in[1];
    const float* W1   = (const float*)d_in[2];
    const float* b1   = (const float*)d_in[3];
    const float* W2   = (const float*)d_in[4];
    const float* b2   = (const float*)d_in[5];
    const float* W3   = (const float*)d_in[6];
    const float* b3   = (const float*)d_in[7];
    const float* Wout = (const float*)d_in[8];
    const float* bout = (const float*)d_in[9];
    float* out = (float*)d_out;

    char* p = (char*)d_ws;
    auto alloc = [&](size_t bytes) -> void* {
        void* r = (void*)p;
        p += (bytes + 255) & ~(size_t)255;
        return r;
    };
    int*    bcnt    = (int*)alloc((size_t)B * CSTRIDE * 4);
    int*    bbase   = (int*)alloc(((size_t)B + 1) * 4);
    uint*   tmp     = (uint*)alloc((size_t)B * BCAP * 4);
    int*    colv    = (int*)alloc((size_t)E * 4);
    int*    row_ptr = (int*)alloc(((size_t)N + 1) * 4);
    float*  inv     = (float*)alloc((size_t)N * 4);
    float*  bc      = (float*)alloc(64 * 4);
    half_t* Wh1     = (half_t*)alloc(128 * 128 * 2);
    half_t* Wh2     = (half_t*)alloc(128 * 128 * 2);
    half_t* Whc     = (half_t*)alloc(64 * 128 * 2);
    half_t* hb      = (half_t*)alloc((size_t)N * 128 * 2);
    half_t* tb      = (half_t*)alloc((size_t)N * 128 * 2);

    const int nSort = (E + CHUNK - 1) / CHUNK;   // 196
    const int nGemm = (N + 127) / 128;           // 782
    const int gAgg  = (N + 3) / 4;

    hipMemsetAsync(bcnt, 0, (size_t)B * CSTRIDE * 4, stream);
    // mega0: edge sort || weight preps (single fp16 weights)
    k_mega0<<<nSort + 128 + 33, 256, 0, stream>>>(ei, W1, W2, W3, Wout, b3, bout,
                                                  bcnt, tmp, Wh1, Wh2, Whc, bc,
                                                  E, nSort);
    // mid: per-bucket histogram -> inv || bucket scan
    k_mid<<<B + 1, 256, 0, stream>>>(tmp, bcnt, inv, bbase, row_ptr, N, B);
    // mega1: gemm1 (inv-scaled) || B1 (CSR placement)
    k_mega1<<<nGemm + B, 256, 0, stream>>>(x, Wh1, inv, tb, tmp, bcnt, bbase,
                                           row_ptr, colv, N, nGemm);
    // layer 1 agg
    k_agg<128, half_t, true><<<gAgg, 256, 0, stream>>>(tb, colv, row_ptr, inv, b1, hb, N);
    // layer 2
    k_gemm<128><<<nGemm, 256, 0, stream>>>(hb, Wh2, inv, tb, N);
    k_agg<128, half_t, true><<<gAgg, 256, 0, stream>>>(tb, colv, row_ptr, inv, b2, hb, N);
    // layer 3 fused with output projection
    k_gemm<64><<<nGemm, 256, 0, stream>>>(hb, Whc, inv, tb, N);
    k_agg<64, float, false><<<gAgg, 256, 0, stream>>>(tb, colv, row_ptr, inv, bc, out, N);
}

// Round 4
// 357.308 us; speedup vs baseline: 8.2576x; 1.0132x over previous
//
#include <hip/hip_runtime.h>

typedef unsigned int uint;
typedef _Float16 half_t;
typedef __attribute__((ext_vector_type(8))) _Float16 halfx8;
typedef __attribute__((ext_vector_type(4))) float floatx4;
typedef __attribute__((ext_vector_type(4))) uint uintx4;

constexpr int BSHIFT  = 9;         // 512 nodes per bucket
constexpr int BNODES  = 1 << BSHIFT;
constexpr int BCAP    = 9216;      // bucket cap: mean 8192 +11 sigma
constexpr int CSTRIDE = 16;        // one counter per 64B line
constexpr int CHUNK   = 8192;      // edges per sort block

// f32 += f16(lo/hi of packed word) * f32 in ONE VOP3P op (v_fma_mix_f32).
// op_sel_hi[0]=1 -> src0 is f16; op_sel[0] picks the half.
__device__ __forceinline__ void fmix_lo(float& a, uint h2, float w) {
    asm("v_fma_mix_f32 %0, %1, %2, %0 op_sel:[0,0,0] op_sel_hi:[1,0,0]"
        : "+v"(a) : "v"(h2), "v"(w));
}
__device__ __forceinline__ void fmix_hi(float& a, uint h2, float w) {
    asm("v_fma_mix_f32 %0, %1, %2, %0 op_sel:[1,0,0] op_sel_hi:[1,0,0]"
        : "+v"(a) : "v"(h2), "v"(w));
}

// volatile asm 16B gather: compiler cannot sink/serialize these — all loads in
// a step issue back-to-back, giving true 4-deep memory parallelism per wave.
// (VGPR=20 in the prior build proved the compiler kept only ~1 in flight.)
__device__ __forceinline__ halfx8 gload16(const half_t* p) {
    halfx8 r;
    asm volatile("global_load_dwordx4 %0, %1, off" : "=v"(r) : "v"(p));
    return r;
}

// ---------------- mega0: sortA | prepW1 | prepW2 | prepWc --------------------
__global__ __launch_bounds__(256) void k_mega0(
    const int* __restrict__ ei,
    const float* __restrict__ W1, const float* __restrict__ W2,
    const float* __restrict__ W3, const float* __restrict__ Wout,
    const float* __restrict__ b3, const float* __restrict__ bout,
    int* __restrict__ bcnt, uint* __restrict__ tmp,
    half_t* __restrict__ Wh1, half_t* __restrict__ Wh2,
    half_t* __restrict__ Whc, float* __restrict__ bc,
    int E, int nSort) {
    __shared__ __align__(16) char smem[45088];
    const int bx = blockIdx.x, t = threadIdx.x;

    if (bx < nSort) {
        // ---- sortA: per-block LDS counting sort of edges into buckets ----
        uint* ent = (uint*)smem;
        unsigned char* bid = (unsigned char*)(smem + 32768);
        int* hist  = (int*)(smem + 40960);
        int* lbase = hist + 256;
        int* lcur  = hist + 512;
        int* gpos  = hist + 768;
        int* wsum  = hist + 1024;
        const int base = bx * CHUNK;
        const int m = min(CHUNK, E - base);
        hist[t] = 0;
        __syncthreads();
        for (int i = t; i < m; i += 256)
            atomicAdd(&hist[ei[E + base + i] >> BSHIFT], 1);
        __syncthreads();
        {
            int lane = t & 63, w = t >> 6;
            int v = hist[t];
            int incl = v;
            for (int dd = 1; dd < 64; dd <<= 1) { int xsh = __shfl_up(incl, dd); if (lane >= dd) incl += xsh; }
            if (lane == 63) wsum[w] = incl;
            __syncthreads();
            int off = 0;
            for (int i = 0; i < w; i++) off += wsum[i];
            int excl = off + incl - v;
            lbase[t] = excl;
            lcur[t]  = excl;
            gpos[t]  = (v > 0) ? atomicAdd(&bcnt[t * CSTRIDE], v) : 0;
        }
        __syncthreads();
        for (int i = t; i < m; i += 256) {
            int s = ei[base + i];
            int d = ei[E + base + i];
            int b = d >> BSHIFT;
            int pos = atomicAdd(&lcur[b], 1);
            ent[pos] = (uint)s | ((uint)(d & (BNODES - 1)) << 17);   // s < 2^17
            bid[pos] = (unsigned char)b;
        }
        __syncthreads();
        for (int i = t; i < m; i += 256) {
            int b = bid[i];
            int g = gpos[b] + (i - lbase[b]);
            if (g < BCAP) tmp[(size_t)b * BCAP + g] = ent[i];
        }
    } else if (bx < nSort + 64) {
        // ---- prepW1: transpose fp32 W1 -> fp16 Wh1 -----------------------
        int i = (bx - nSort) * 256 + t;
        int k = i >> 7, n = i & 127;
        Wh1[n * 128 + k] = (half_t)W1[k * 128 + n];
    } else if (bx < nSort + 128) {
        // ---- prepW2 ------------------------------------------------------
        int i = (bx - nSort - 64) * 256 + t;
        int k = i >> 7, n = i & 127;
        Wh2[n * 128 + k] = (half_t)W2[k * 128 + n];
    } else {
        // ---- prepWc: Wc = W3@Wout fused transpose; bc = b3@Wout+bout -----
        int i = (bx - nSort - 128) * 256 + t;
        if (i < 128 * 64) {
            int r = i >> 6, j = i & 63;
            float s = 0.0f;
            for (int k = 0; k < 128; k++) s += W3[r * 128 + k] * Wout[k * 64 + j];
            Whc[j * 128 + r] = (half_t)s;
        } else if (i < 128 * 64 + 64) {
            int j = i - 128 * 64;
            float s = bout[j];
            for (int k = 0; k < 128; k++) s += b3[k] * Wout[k * 64 + j];
            bc[j] = s;
        }
    }
}

// ---------------- mid: per-bucket histogram -> inv | bucketScan --------------
__global__ __launch_bounds__(256) void k_mid(
    const uint* __restrict__ tmp, const int* __restrict__ bcnt,
    float* __restrict__ inv, int* __restrict__ bbase,
    int* __restrict__ row_ptr, int N, int B) {
    __shared__ int cnt[BNODES];
    int bx = blockIdx.x, t = threadIdx.x;
    if (bx < B) {
        cnt[t] = 0; cnt[t + 256] = 0;
        __syncthreads();
        int m = min(bcnt[bx * CSTRIDE], BCAP);
        const uint* tp = tmp + (size_t)bx * BCAP;
        for (int i = t; i < m; i += 256) atomicAdd(&cnt[tp[i] >> 17], 1);
        __syncthreads();
        int nbase = bx << BSHIFT;
        int n0 = nbase + t, n1 = nbase + t + 256;
        if (n0 < N) inv[n0] = rsqrtf((float)(cnt[t] + 1));       // +1 self-loop
        if (n1 < N) inv[n1] = rsqrtf((float)(cnt[t + 256] + 1));
    } else {
        int* wsum = cnt;   // reuse
        int lane = t & 63, w = t >> 6;
        int v = (t < B) ? min(bcnt[t * CSTRIDE], BCAP) : 0;
        int incl = v;
        for (int d = 1; d < 64; d <<= 1) { int x = __shfl_up(incl, d); if (lane >= d) incl += x; }
        if (lane == 63) wsum[w] = incl;
        __syncthreads();
        int off = 0;
        for (int i = 0; i < w; i++) off += wsum[i];
        int excl = off + incl - v;
        if (t <= B) bbase[t] = excl;
        if (t == B) row_ptr[N] = excl;
    }
}

// ---------------- mega1: gemm1 (fp32 A, single fp16 W, inv epilogue) | B1 ----
__global__ __launch_bounds__(256) void k_mega1(
    const float* __restrict__ A, const half_t* __restrict__ Wh,
    const float* __restrict__ inv, half_t* __restrict__ Out,
    const uint* __restrict__ tmp, const int* __restrict__ bcnt,
    const int* __restrict__ bbase, int* __restrict__ row_ptr,
    int* __restrict__ colv, int N, int nGemm) {
    __shared__ __align__(16) char smem1[128 * 136 * 2];
    const int bx = blockIdx.x, tid = threadIdx.x;

    if (bx >= nGemm) {
        // ---- B1: per-bucket node histogram -> row_ptr; place src into CSR
        int* cnt = (int*)smem1;             // [512]
        int* cur = cnt + BNODES;            // [512]
        int* wsum2 = cur + BNODES;          // [4]
        int b = bx - nGemm, t = tid;
        int base = bbase[b], nbase = b << BSHIFT;
        cnt[t] = 0; cnt[t + 256] = 0;
        __syncthreads();
        int m = min(bcnt[b * CSTRIDE], BCAP);
        const uint* tp = tmp + (size_t)b * BCAP;
        for (int i = t; i < m; i += 256) atomicAdd(&cnt[tp[i] >> 17], 1);
        __syncthreads();
        int lane = t & 63, w = t >> 6;
        int c0 = cnt[2 * t], c1 = cnt[2 * t + 1];
        int v = c0 + c1;
        int incl = v;
        for (int dd = 1; dd < 64; dd <<= 1) { int x = __shfl_up(incl, dd); if (lane >= dd) incl += x; }
        if (lane == 63) wsum2[w] = incl;
        __syncthreads();
        int off = 0;
        for (int i = 0; i < w; i++) off += wsum2[i];
        int excl = off + incl - v;
        int n0 = nbase + 2 * t, n1 = nbase + 2 * t + 1;
        __syncthreads();
        cur[2 * t] = excl; cur[2 * t + 1] = excl + c0;
        if (n0 < N) row_ptr[n0] = base + excl;
        if (n1 < N) row_ptr[n1] = base + excl + c0;
        __syncthreads();
        for (int i = t; i < m; i += 256) {
            uint wv = tp[i];
            int dlo = wv >> 17, s = (int)(wv & 0x1FFFFu);
            int pos = atomicAdd(&cur[dlo], 1);
            colv[base + pos] = s;           // bucket-local, L2-coalesced
        }
        return;
    }
    // ---- gemm1: single-pass fp16 W, fp32 A -> fp16, inv-scaled epilogue ---
    half_t* lds = (half_t*)smem1;
    for (int i = tid; i < 128 * 16; i += 256) {
        int r = i >> 4, c = i & 15;
        *(halfx8*)&lds[r * 136 + c * 8] = *(const halfx8*)&Wh[(size_t)r * 128 + c * 8];
    }
    __syncthreads();
    const int w = tid >> 6, lane = tid & 63;
    const int q = lane >> 4, m = lane & 15;
    const int rowBase = bx * 128 + w * 32;
    int arow[2];
#pragma unroll
    for (int rt = 0; rt < 2; ++rt) {
        int r = rowBase + rt * 16 + m;
        arow[rt] = (r < N) ? r : (N - 1);
    }
    floatx4 acc[2][8];
#pragma unroll
    for (int rt = 0; rt < 2; ++rt)
#pragma unroll
        for (int ct = 0; ct < 8; ++ct) acc[rt][ct] = (floatx4)0.0f;
#pragma unroll
    for (int kk = 0; kk < 4; ++kk) {
        halfx8 a[2];
#pragma unroll
        for (int rt = 0; rt < 2; ++rt) {
            const float* ap = A + (size_t)arow[rt] * 128 + kk * 32 + q * 8;
            floatx4 f0 = *(const floatx4*)ap;
            floatx4 f1 = *(const floatx4*)(ap + 4);
#pragma unroll
            for (int i = 0; i < 4; i++) { a[rt][i] = (half_t)f0[i]; a[rt][4 + i] = (half_t)f1[i]; }
        }
#pragma unroll
        for (int ct = 0; ct < 8; ++ct) {
            halfx8 bh = *(const halfx8*)&lds[(ct * 16 + m) * 136 + kk * 32 + q * 8];
#pragma unroll
            for (int rt = 0; rt < 2; ++rt)
                acc[rt][ct] = __builtin_amdgcn_mfma_f32_16x16x32_f16(a[rt], bh, acc[rt][ct], 0, 0, 0);
        }
    }
#pragma unroll
    for (int rt = 0; rt < 2; ++rt)
#pragma unroll
        for (int r = 0; r < 4; ++r) {
            int orow = rowBase + rt * 16 + q * 4 + r;
            if (orow < N) {
                float sc = inv[orow];       // fold inv[row] into stored value
#pragma unroll
                for (int ct = 0; ct < 8; ++ct)
                    Out[(size_t)orow * 128 + ct * 16 + m] = (half_t)(sc * acc[rt][ct][r]);
            }
        }
}

// ---- GEMM (fp16 A, single fp16 W): Out = inv[row] * (A @ Wh) ----------------
template <int NOUT>
__global__ __launch_bounds__(256) void k_gemm(const half_t* __restrict__ A,
                                              const half_t* __restrict__ Wh,
                                              const float* __restrict__ inv,
                                              half_t* __restrict__ Out, int nRows) {
    constexpr int CT = NOUT / 16;
    __shared__ __align__(16) half_t lds[NOUT * 136];
    const int tid = threadIdx.x;
    for (int i = tid; i < NOUT * 16; i += 256) {
        int r = i >> 4, c = i & 15;
        *(halfx8*)&lds[r * 136 + c * 8] = *(const halfx8*)&Wh[(size_t)r * 128 + c * 8];
    }
    __syncthreads();
    const int w = tid >> 6, lane = tid & 63;
    const int q = lane >> 4, m = lane & 15;
    const int rowBase = blockIdx.x * 128 + w * 32;
    int arow[2];
#pragma unroll
    for (int rt = 0; rt < 2; ++rt) {
        int r = rowBase + rt * 16 + m;
        arow[rt] = (r < nRows) ? r : (nRows - 1);
    }
    floatx4 acc[2][CT];
#pragma unroll
    for (int rt = 0; rt < 2; ++rt)
#pragma unroll
        for (int ct = 0; ct < CT; ++ct) acc[rt][ct] = (floatx4)0.0f;
#pragma unroll
    for (int kk = 0; kk < 4; ++kk) {
        halfx8 a[2];
#pragma unroll
        for (int rt = 0; rt < 2; ++rt)
            a[rt] = *(const halfx8*)(A + (size_t)arow[rt] * 128 + kk * 32 + q * 8);
#pragma unroll
        for (int ct = 0; ct < CT; ++ct) {
            halfx8 bh = *(const halfx8*)&lds[(ct * 16 + m) * 136 + kk * 32 + q * 8];
#pragma unroll
            for (int rt = 0; rt < 2; ++rt)
                acc[rt][ct] = __builtin_amdgcn_mfma_f32_16x16x32_f16(a[rt], bh, acc[rt][ct], 0, 0, 0);
        }
    }
#pragma unroll
    for (int rt = 0; rt < 2; ++rt)
#pragma unroll
        for (int r = 0; r < 4; ++r) {
            int orow = rowBase + rt * 16 + q * 4 + r;
            if (orow < nRows) {
                float sc = inv[orow];
#pragma unroll
                for (int ct = 0; ct < CT; ++ct)
                    Out[(size_t)orow * NOUT + ct * 16 + m] = (half_t)(sc * acc[rt][ct][r]);
            }
        }
}

// ---- aggregation: per-row wave, FORCED 4-deep gather pipeline ---------------
// asm global_load_dwordx4 x4 back-to-back -> one vmcnt(0) -> sched_barrier(0)
// (sched_barrier REQUIRED: compiler doesn't model asm loads in its vmcnt
//  accounting, so dependent FMAs must be pinned after the explicit wait.)
// self-row term consumed AFTER the edge loop so its load overlaps everything.
template <int CH, typename OT, bool RELU>
__global__ __launch_bounds__(256) void k_agg(const half_t* __restrict__ tb,
                                             const int* __restrict__ colv,
                                             const int* __restrict__ row_ptr,
                                             const float* __restrict__ inv,
                                             const float* __restrict__ bias,
                                             OT* __restrict__ out, int N) {
    constexpr int L = CH / 8;     // lanes per row (16 or 8)
    constexpr int G = 64 / L;     // edge groups (4 or 8)
    int wid = threadIdx.x >> 6, lane = threadIdx.x & 63;
    int d = blockIdx.x * 4 + wid;
    if (d >= N) return;
    int beg = row_ptr[d], end = row_ptr[d + 1];
    int grp = lane / L;
    int choff = (lane % L) * 8;
    const float one = 1.0f;
    const half_t* tbc = tb + choff;

    // issue early; consumed only after the edge loop (overlaps whole loop)
    halfx8 pself = *(const halfx8*)(tbc + (size_t)d * CH);
    float isd = inv[d];

    float af[8];
#pragma unroll
    for (int c = 0; c < 8; c++) af[c] = 0.0f;

    for (int e0 = beg; e0 < end; e0 += 64) {
        int me = e0 + lane;
        int sl = 0; float wl = 0.0f;
        if (me < end) { sl = colv[me]; wl = 1.0f; }
        int cnt = end - e0; if (cnt > 64) cnt = 64;
        int j = 0;
        // ---- main: full 4*G-edge steps, all valid, weight == 1 ----------
        for (; j + 4 * G <= cnt; j += 4 * G) {
            int s4[4];
#pragma unroll
            for (int u = 0; u < 4; u++) s4[u] = __shfl(sl, j + u * G + grp);
            halfx8 pv[4];
#pragma unroll
            for (int u = 0; u < 4; u++)
                pv[u] = gload16(tbc + (size_t)s4[u] * CH);
            asm volatile("s_waitcnt vmcnt(0)" ::: "memory");
            __builtin_amdgcn_sched_barrier(0);
#pragma unroll
            for (int u = 0; u < 4; u++) {
                uintx4 pw = __builtin_bit_cast(uintx4, pv[u]);
#pragma unroll
                for (int c = 0; c < 8; c++) {
                    if (c & 1) fmix_hi(af[c], pw[c >> 1], one);
                    else       fmix_lo(af[c], pw[c >> 1], one);
                }
            }
        }
        // ---- tail: one predicated 4-deep step (<4*G edges remain) -------
        if (j < cnt) {
            int s4[4]; float w4[4];
#pragma unroll
            for (int u = 0; u < 4; u++) {
                int idx = j + u * G + grp;
                s4[u] = __shfl(sl, idx);
                w4[u] = __shfl(wl, idx);
            }
            halfx8 pv[4];
#pragma unroll
            for (int u = 0; u < 4; u++)
                pv[u] = gload16(tbc + (size_t)s4[u] * CH);
            asm volatile("s_waitcnt vmcnt(0)" ::: "memory");
            __builtin_amdgcn_sched_barrier(0);
#pragma unroll
            for (int u = 0; u < 4; u++) {
                uintx4 pw = __builtin_bit_cast(uintx4, pv[u]);
#pragma unroll
                for (int c = 0; c < 8; c++) {
                    if (c & 1) fmix_hi(af[c], pw[c >> 1], w4[u]);
                    else       fmix_lo(af[c], pw[c >> 1], w4[u]);
                }
            }
        }
    }
    // self term: added once (group 0 only), load long since in flight
    {
        float ws0 = (grp == 0) ? 1.0f : 0.0f;
        uintx4 pw = __builtin_bit_cast(uintx4, pself);
#pragma unroll
        for (int c = 0; c < 8; c++) {
            if (c & 1) fmix_hi(af[c], pw[c >> 1], ws0);
            else       fmix_lo(af[c], pw[c >> 1], ws0);
        }
    }
#pragma unroll
    for (int msk = L; msk < 64; msk <<= 1)
#pragma unroll
        for (int c = 0; c < 8; c++)
            af[c] += __shfl_xor(af[c], msk);

    if (lane < L) {
        int ch = lane * 8;
        floatx4 b0 = *(const floatx4*)(bias + ch);
        floatx4 b1 = *(const floatx4*)(bias + ch + 4);
#pragma unroll
        for (int c = 0; c < 8; c++) {
            af[c] = isd * af[c] + ((c < 4) ? b0[c] : b1[c - 4]);
            if (RELU) af[c] = fmaxf(af[c], 0.0f);
        }
        if constexpr (sizeof(OT) == 2) {
            halfx8 o;
#pragma unroll
            for (int c = 0; c < 8; c++) o[c] = (half_t)af[c];
            *(halfx8*)((half_t*)out + (size_t)d * CH + ch) = o;
        } else {
            floatx4 o0, o1;
#pragma unroll
            for (int c = 0; c < 4; c++) { o0[c] = af[c]; o1[c] = af[c + 4]; }
            *(floatx4*)((float*)out + (size_t)d * CH + ch) = o0;
            *(floatx4*)((float*)out + (size_t)d * CH + ch + 4) = o1;
        }
    }
}

// ---- host -------------------------------------------------------------------
extern "C" void kernel_launch(void* const* d_in, const int* in_sizes, int n_in,
                              void* d_out, int out_size, void* d_ws, size_t ws_size,
                              hipStream_t stream) {
    const int N = in_sizes[0] / 128;   // 100000
    const int E = in_sizes[1] / 2;     // 1600000
    const int B = (N + BNODES - 1) >> BSHIFT;   // 196

    const float* x    = (const float*)d_in[0];
    const int*   ei   = (const int*)d_in[1];
    const float* W1   = (const float*)d_in[2];
    const float* b1   = (const float*)d_in[3];
    const float* W2   = (const float*)d_in[4];
    const float* b2   = (const float*)d_in[5];
    const float* W3   = (const float*)d_in[6];
    const float* b3   = (const float*)d_in[7];
    const float* Wout = (const float*)d_in[8];
    const float* bout = (const float*)d_in[9];
    float* out = (float*)d_out;

    char* p = (char*)d_ws;
    auto alloc = [&](size_t bytes) -> void* {
        void* r = (void*)p;
        p += (bytes + 255) & ~(size_t)255;
        return r;
    };
    int*    bcnt    = (int*)alloc((size_t)B * CSTRIDE * 4);
    int*    bbase   = (int*)alloc(((size_t)B + 1) * 4);
    uint*   tmp     = (uint*)alloc((size_t)B * BCAP * 4);
    int*    colv    = (int*)alloc((size_t)E * 4);
    int*    row_ptr = (int*)alloc(((size_t)N + 1) * 4);
    float*  inv     = (float*)alloc((size_t)N * 4);
    float*  bc      = (float*)alloc(64 * 4);
    half_t* Wh1     = (half_t*)alloc(128 * 128 * 2);
    half_t* Wh2     = (half_t*)alloc(128 * 128 * 2);
    half_t* Whc     = (half_t*)alloc(64 * 128 * 2);
    half_t* hb      = (half_t*)alloc((size_t)N * 128 * 2);
    half_t* tb      = (half_t*)alloc((size_t)N * 128 * 2);

    const int nSort = (E + CHUNK - 1) / CHUNK;   // 196
    const int nGemm = (N + 127) / 128;           // 782
    const int gAgg  = (N + 3) / 4;

    hipMemsetAsync(bcnt, 0, (size_t)B * CSTRIDE * 4, stream);
    // mega0: edge sort || weight preps (single fp16 weights)
    k_mega0<<<nSort + 128 + 33, 256, 0, stream>>>(ei, W1, W2, W3, Wout, b3, bout,
                                                  bcnt, tmp, Wh1, Wh2, Whc, bc,
                                                  E, nSort);
    // mid: per-bucket histogram -> inv || bucket scan
    k_mid<<<B + 1, 256, 0, stream>>>(tmp, bcnt, inv, bbase, row_ptr, N, B);
    // mega1: gemm1 (inv-scaled) || B1 (CSR placement)
    k_mega1<<<nGemm + B, 256, 0, stream>>>(x, Wh1, inv, tb, tmp, bcnt, bbase,
                                           row_ptr, colv, N, nGemm);
    // layer 1 agg
    k_agg<128, half_t, true><<<gAgg, 256, 0, stream>>>(tb, colv, row_ptr, inv, b1, hb, N);
    // layer 2
    k_gemm<128><<<nGemm, 256, 0, stream>>>(hb, Wh2, inv, tb, N);
    k_agg<128, half_t, true><<<gAgg, 256, 0, stream>>>(tb, colv, row_ptr, inv, b2, hb, N);
    // layer 3 fused with output projection
    k_gemm<64><<<nGemm, 256, 0, stream>>>(hb, Whc, inv, tb, N);
    k_agg<64, float, false><<<gAgg, 256, 0, stream>>>(tb, colv, row_ptr, inv, bc, out, N);
}